// Round 1
// baseline (30384.100 us; speedup 1.0000x reference)
//
#include <hip/hip_runtime.h>

#define SEQ  1000
#define IDIM 900
#define H    4096

// ---------------------------------------------------------------------------
// Fast tanh: tanh(x) = sign(x) * (1 - e^{-2|x|}) / (1 + e^{-2|x|})
// ---------------------------------------------------------------------------
__device__ __forceinline__ float tanh_fast(float x) {
    float ax = __builtin_fabsf(x);
    float e  = __expf(-2.0f * ax);
    float t  = (1.0f - e) / (1.0f + e);
    return __builtin_copysignf(t, x);
}

// ---------------------------------------------------------------------------
// Persistent recurrent kernel.
// Grid: 256 blocks x 512 threads (8 waves), cooperative launch (co-resident).
// quad q = b>>2 owns rows [64q, 64q+64); member m = b&3 owns cols [1024m, +1024).
// Lane = row offset within quad; wave w covers cols [1024m + 128w, +128).
// Each lane holds 128 fp32 W_hh weights in VGPRs for the whole kernel.
// Communication: atomicAdd partial row-sums into pre[t+1], per-quad flag
// counters (qflag[q] == 4*t  <=>  all contributions to pre[t] are complete).
// ---------------------------------------------------------------------------
__global__ __launch_bounds__(512, 2) void esn_recurrent(
    const float* __restrict__ Whh,    // H*H row-major
    float*       __restrict__ pre,    // SEQ*H  (ws): pre-activations, init = X@W_ih^T
    float*       __restrict__ states, // SEQ*H  (d_out section)
    unsigned int* __restrict__ qflag) // 64 counters (zeroed before launch)
{
    const int b    = blockIdx.x;
    const int q    = b >> 2;          // 0..63
    const int m    = b & 3;           // 0..3
    const int tid  = threadIdx.x;
    const int wave = tid >> 6;        // 0..7
    const int lane = tid & 63;        // 0..63
    const int row  = (q << 6) + lane;           // my output row
    const int col0 = (m << 10) + (wave << 7);   // my wave's first col (global)

    // ---- load my 128 weights into registers (once) ----
    float w[128];
    {
        const float* wp = Whh + (size_t)row * H + col0;
        #pragma unroll
        for (int k = 0; k < 128; k += 4) {
            float4 v = *(const float4*)(wp + k);
            w[k] = v.x; w[k + 1] = v.y; w[k + 2] = v.z; w[k + 3] = v.w;
        }
    }

    __shared__ float s_lds[1024];     // tanh(pre[t]) for my 1024 cols
    __shared__ float red[8][64];      // cross-wave reduction

    const int qlo = m << 4;           // quads contributing to my col slice: [16m, 16m+16)

    for (int t = 0; t < SEQ; ++t) {
        // ---- 1. wait until pre[t] for my cols is complete ----
        if (t > 0) {
            if (wave == 0) {
                const int qq = qlo + (lane & 15);
                while (__hip_atomic_load(&qflag[qq], __ATOMIC_RELAXED,
                                         __HIP_MEMORY_SCOPE_AGENT) < 4u * (unsigned)t) {
                    __builtin_amdgcn_s_sleep(1);
                }
            }
            __syncthreads();
            __builtin_amdgcn_fence(__ATOMIC_ACQUIRE, "agent");
        }

        // ---- 2. read pre[t][my cols] (agent-scope loads: bypass stale L2),
        //         tanh, stash in LDS; blocks 0..3 also write states[t] ----
        {
            float* pt = pre + (size_t)t * H + (m << 10);
            float v0 = __hip_atomic_load(&pt[2 * tid],     __ATOMIC_RELAXED, __HIP_MEMORY_SCOPE_AGENT);
            float v1 = __hip_atomic_load(&pt[2 * tid + 1], __ATOMIC_RELAXED, __HIP_MEMORY_SCOPE_AGENT);
            float s0 = tanh_fast(v0);
            float s1 = tanh_fast(v1);
            s_lds[2 * tid]     = s0;
            s_lds[2 * tid + 1] = s1;
            if (b < 4) {  // b==m for b<4: together cover all 4096 cols
                float* so = states + (size_t)t * H + (m << 10);
                so[2 * tid]     = s0;
                so[2 * tid + 1] = s1;
            }
        }

        if (t == SEQ - 1) break;      // uniform exit: states[SEQ-1] written
        __syncthreads();

        // ---- 3. my partial dot: row x my 128 cols (s is wave-uniform -> LDS broadcast) ----
        float a0 = 0.f, a1 = 0.f, a2 = 0.f, a3 = 0.f;
        {
            const float4* sv = (const float4*)(s_lds + (wave << 7));
            #pragma unroll
            for (int j = 0; j < 32; ++j) {
                float4 v = sv[j];
                a0 += w[4 * j + 0] * v.x;
                a1 += w[4 * j + 1] * v.y;
                a2 += w[4 * j + 2] * v.z;
                a3 += w[4 * j + 3] * v.w;
            }
        }
        red[wave][lane] = (a0 + a1) + (a2 + a3);
        __syncthreads();

        // ---- 4. cross-wave reduce + atomic scatter into pre[t+1], then flag ----
        if (wave == 0) {
            float sum = 0.f;
            #pragma unroll
            for (int ww = 0; ww < 8; ++ww) sum += red[ww][lane];
            atomicAdd(&pre[(size_t)(t + 1) * H + row], sum);
            __threadfence();          // drain my atomics before flagging
            if (lane == 0) {
                __hip_atomic_fetch_add(&qflag[q], 1u, __ATOMIC_RELEASE,
                                       __HIP_MEMORY_SCOPE_AGENT);
            }
        }
        // next iteration's top __syncthreads keeps s_lds/red overwrite safe
    }
}

// ---------------------------------------------------------------------------
// Generic fp32 tiled GEMM:  C[MxN] = A[MxK] * B[NxK]^T   (both row-major)
// mode 0: A is a plain array (lda).
// mode 1: A is the virtual ext matrix: row t, col k: k==0 -> 1;
//         1<=k<=900 -> X[t][k-1]; 901<=k<=4996 -> S[t][k-901].
// ---------------------------------------------------------------------------
#define BM 64
#define BN 64
#define BK 32

__global__ __launch_bounds__(256) void gemm_abt(
    const float* __restrict__ A, int lda,
    const float* __restrict__ B, int ldb,
    float*       __restrict__ C, int ldc,
    int M, int N, int K, int mode,
    const float* __restrict__ X, const float* __restrict__ S)
{
    __shared__ float As[BK][BM + 1];
    __shared__ float Bs[BK][BN + 1];

    const int tid = threadIdx.x;
    const int n0  = blockIdx.x * BN;
    const int m0  = blockIdx.y * BM;
    const int tx  = tid & 15;
    const int ty  = tid >> 4;

    float c[4][4] = {};

    for (int k0 = 0; k0 < K; k0 += BK) {
        #pragma unroll
        for (int p = 0; p < 8; ++p) {
            const int idx = tid + p * 256;
            const int mm  = idx >> 5;     // 0..63
            const int kk  = idx & 31;     // 0..31
            const int gk  = k0 + kk;

            // A tile
            float av = 0.f;
            const int gm = m0 + mm;
            if (gm < M && gk < K) {
                if (mode == 0) {
                    av = A[(size_t)gm * lda + gk];
                } else {
                    if (gk == 0)          av = 1.0f;
                    else if (gk <= IDIM)  av = X[(size_t)gm * IDIM + (gk - 1)];
                    else                  av = S[(size_t)gm * H + (gk - 1 - IDIM)];
                }
            }
            As[kk][mm] = av;

            // B tile
            float bv = 0.f;
            const int gn = n0 + mm;
            if (gn < N && gk < K) bv = B[(size_t)gn * ldb + gk];
            Bs[kk][mm] = bv;
        }
        __syncthreads();

        #pragma unroll
        for (int kk = 0; kk < BK; ++kk) {
            float a[4], bb[4];
            #pragma unroll
            for (int i = 0; i < 4; ++i) a[i]  = As[kk][ty * 4 + i];
            #pragma unroll
            for (int j = 0; j < 4; ++j) bb[j] = Bs[kk][tx * 4 + j];
            #pragma unroll
            for (int i = 0; i < 4; ++i)
                #pragma unroll
                for (int j = 0; j < 4; ++j)
                    c[i][j] += a[i] * bb[j];
        }
        __syncthreads();
    }

    #pragma unroll
    for (int i = 0; i < 4; ++i) {
        const int gm = m0 + ty * 4 + i;
        if (gm >= M) continue;
        #pragma unroll
        for (int j = 0; j < 4; ++j) {
            const int gn = n0 + tx * 4 + j;
            if (gn < N) C[(size_t)gm * ldc + gn] = c[i][j];
        }
    }
}

// ---------------------------------------------------------------------------
// Launcher
// ---------------------------------------------------------------------------
extern "C" void kernel_launch(void* const* d_in, const int* in_sizes, int n_in,
                              void* d_out, int out_size, void* d_ws, size_t ws_size,
                              hipStream_t stream) {
    const float* inputs = (const float*)d_in[0];
    // d_in[1] = initial state (all zeros) — folded out analytically
    const float* W_ih   = (const float*)d_in[2];
    const float* W_hh   = (const float*)d_in[3];
    const float* W_out  = (const float*)d_in[4];

    float* out    = (float*)d_out;                 // SEQ*IDIM
    float* states = out + (size_t)SEQ * IDIM;      // SEQ*H

    float* pre = (float*)d_ws;                     // SEQ*H fp32
    unsigned int* qflag =
        (unsigned int*)((char*)d_ws + (size_t)SEQ * H * sizeof(float));

    hipMemsetAsync(qflag, 0, 64 * sizeof(unsigned int), stream);

    // Phase 0: pre[t][r] = sum_i X[t][i] * W_ih[r][i]
    gemm_abt<<<dim3(H / BN, (SEQ + BM - 1) / BM), 256, 0, stream>>>(
        inputs, IDIM, W_ih, IDIM, pre, H, SEQ, H, IDIM, 0, nullptr, nullptr);

    // Phase 1: persistent sequential recurrence (cooperative: all 256 blocks resident)
    {
        const float* whh_p = W_hh;
        float* pre_p = pre;
        float* st_p  = states;
        unsigned int* qf_p = qflag;
        void* args[] = { (void*)&whh_p, (void*)&pre_p, (void*)&st_p, (void*)&qf_p };
        hipLaunchCooperativeKernel((const void*)esn_recurrent,
                                   dim3(256), dim3(512), args, 0, stream);
    }

    // Phase 2: outputs[t][i] = sum_k ext[t][k] * W_out[i][k]  (ext built on the fly)
    gemm_abt<<<dim3((IDIM + BN - 1) / BN, (SEQ + BM - 1) / BM), 256, 0, stream>>>(
        nullptr, 0, W_out, 1 + IDIM + H, out, IDIM,
        SEQ, IDIM, 1 + IDIM + H, 1, inputs, states);
}